// Round 1
// 859.548 us; speedup vs baseline: 1.3546x; 1.3546x over previous
//
#include <hip/hip_runtime.h>
#include <hip/hip_bf16.h>
#include <cstdint>
#include <cstddef>

#define B_  2
#define S_  2048
#define D_  1024
#define H_  16
#define DH_ 64
#define OUT_ELEMS ((size_t)B_ * S_ * D_)   // 4,194,304; aws follows in d_out

typedef unsigned short u16;
typedef __attribute__((ext_vector_type(8))) short short8;
typedef __attribute__((ext_vector_type(4))) float f32x4;

__device__ __forceinline__ float bf2f(u16 u) {
    union { unsigned int i; float f; } x;
    x.i = ((unsigned int)u) << 16;
    return x.f;
}
__device__ __forceinline__ u16 f2bf(float f) {
    union { float f; unsigned int i; } x; x.f = f;
    unsigned int r = x.i + 0x7fffu + ((x.i >> 16) & 1u);  // round-to-nearest-even
    return (u16)(r >> 16);
}

#define LDSTR 72  // 64 + 8 pad; 144 B row stride (16B-aligned, 2-way bank alias = free)

// ---------------------------------------------------------------------------
// Dtype probe: read even u16s of q. If the data is fp32, these are mantissa
// bits -> as bf16 ~89% are wild. flag=1 => external data is fp32.
// ---------------------------------------------------------------------------
__global__ __launch_bounds__(64) void detect_kernel(const void* q, unsigned int* flag)
{
    const int lane = threadIdx.x;
    const u16 e = ((const u16*)q)[lane * 2];
    const float v = bf2f(e);
    const float a = fabsf(v);
    const bool wild = !(a <= 100.f) || (a != 0.f && a < 1e-6f);  // !(a<=100) catches NaN
    unsigned long long m = __ballot(wild);
    if (lane == 0) *flag = (__popcll(m) >= 16) ? 1u : 0u;
}

// ---------------------------------------------------------------------------
// Convert the 4 bias vectors (1024 elems each) to bf16 in ws.
// ---------------------------------------------------------------------------
__global__ __launch_bounds__(256) void convert_bias_kernel(
    const void* bq, const void* bk, const void* bv, const void* bo,
    u16* __restrict__ dst, const unsigned int* __restrict__ flag)
{
    const bool ext32 = flag[0] != 0;
    const int which = blockIdx.y;
    const void* src = which == 0 ? bq : which == 1 ? bk : which == 2 ? bv : bo;
    u16* d = dst + which * 1024;
    const int tid = threadIdx.x;
    #pragma unroll
    for (int i = 0; i < 4; ++i) {
        const int idx = i * 256 + tid;
        d[idx] = ext32 ? f2bf(((const float*)src)[idx]) : ((const u16*)src)[idx];
    }
}

// ---------------------------------------------------------------------------
// Transpose weights into N x K bf16 layout via 64x64 LDS tiles.
// which<3: W (H,D,DH) -> WT[n=h*64+dh][d]   which==3: Wo (D,D) -> WoT[n][d]
// ---------------------------------------------------------------------------
__global__ __launch_bounds__(256) void transpose_weights_kernel(
    const void* Wq, const void* Wk, const void* Wv, const void* Wo,
    u16* __restrict__ WqT, u16* __restrict__ WkT,
    u16* __restrict__ WvT, u16* __restrict__ WoT,
    const unsigned int* __restrict__ flag)
{
    __shared__ u16 t[64][65];
    const bool ext32 = flag[0] != 0;
    const int which = blockIdx.y;
    const void* src = which == 0 ? Wq : which == 1 ? Wk : which == 2 ? Wv : Wo;
    u16* dst = which == 0 ? WqT : which == 1 ? WkT : which == 2 ? WvT : WoT;
    const int tile = blockIdx.x;            // 0..255
    const int tid = threadIdx.x;
    const int rr = tid >> 6;                // 0..3
    const int cc = tid & 63;                // 0..63

    if (which < 3) {
        const int h = tile >> 4, d0 = (tile & 15) * 64;
        #pragma unroll
        for (int i = 0; i < 16; ++i) {
            int r = rr + i * 4;
            size_t idx = ((size_t)(h * 1024 + d0 + r)) * 64 + cc;     // W[h][d0+r][cc]
            t[r][cc] = ext32 ? f2bf(((const float*)src)[idx]) : ((const u16*)src)[idx];
        }
        __syncthreads();
        #pragma unroll
        for (int i = 0; i < 16; ++i) {
            int c = rr + i * 4;  // dh
            dst[((size_t)(h * 64 + c)) * 1024 + d0 + cc] = t[cc][c];  // WT[h*64+c][d0+cc]
        }
    } else {
        const int d0 = (tile >> 4) * 64, n0 = (tile & 15) * 64;
        #pragma unroll
        for (int i = 0; i < 16; ++i) {
            int r = rr + i * 4;
            size_t idx = (size_t)(d0 + r) * 1024 + n0 + cc;           // Wo[d0+r][n0+cc]
            t[r][cc] = ext32 ? f2bf(((const float*)src)[idx]) : ((const u16*)src)[idx];
        }
        __syncthreads();
        #pragma unroll
        for (int i = 0; i < 16; ++i) {
            int c = rr + i * 4;
            dst[(size_t)(n0 + c) * 1024 + d0 + cc] = t[cc][c];        // WoT[n0+c][d0+cc]
        }
    }
}

// ---------------------------------------------------------------------------
// 128x128-tile bf16 MFMA GEMM: out = A(MxK) * BT(NxK)^T + bias(N), N=1024.
// a_ext: A is external (flag dtype); else A is internal bf16.
// mode 0: out[b][h][s][dh] bf16   mode 1: out[b][h][dh][s] bf16
// mode 2: out[m][n] in external dtype (final output)
// ---------------------------------------------------------------------------
__global__ __launch_bounds__(256) void gemm_bias_kernel(
    const void* __restrict__ A, const u16* __restrict__ BT,
    const u16* __restrict__ bias, void* __restrict__ out,
    int M, int K, int mode, int a_ext, const unsigned int* __restrict__ flag)
{
    __shared__ u16 lA[128 * LDSTR];
    __shared__ u16 lB[128 * LDSTR];
    const bool ext32 = flag[0] != 0;
    const int tid = threadIdx.x;
    const int wave = tid >> 6, lane = tid & 63;
    const int m0 = blockIdx.x * 128, n0 = blockIdx.y * 128;
    const int wm = (wave >> 1) * 64, wn = (wave & 1) * 64;

    f32x4 acc[4][4];
    #pragma unroll
    for (int i = 0; i < 4; ++i)
        #pragma unroll
        for (int j = 0; j < 4; ++j)
            acc[i][j] = (f32x4){0.f, 0.f, 0.f, 0.f};

    for (int k0 = 0; k0 < K; k0 += 64) {
        if (a_ext && ext32) {
            const float* Af = (const float*)A;
            #pragma unroll
            for (int it = 0; it < 4; ++it) {
                int e = (it * 256 + tid) * 8;
                int r = e >> 6, c = e & 63;
                const float4 f0 = *(const float4*)&Af[(size_t)(m0 + r) * K + k0 + c];
                const float4 f1 = *(const float4*)&Af[(size_t)(m0 + r) * K + k0 + c + 4];
                short8 o;
                o[0] = (short)f2bf(f0.x); o[1] = (short)f2bf(f0.y);
                o[2] = (short)f2bf(f0.z); o[3] = (short)f2bf(f0.w);
                o[4] = (short)f2bf(f1.x); o[5] = (short)f2bf(f1.y);
                o[6] = (short)f2bf(f1.z); o[7] = (short)f2bf(f1.w);
                *(short8*)&lA[r * LDSTR + c] = o;
                *(short8*)&lB[r * LDSTR + c] = *(const short8*)&BT[(size_t)(n0 + r) * K + k0 + c];
            }
        } else {
            const u16* Ab = (const u16*)A;
            #pragma unroll
            for (int it = 0; it < 4; ++it) {
                int e = (it * 256 + tid) * 8;
                int r = e >> 6, c = e & 63;
                *(short8*)&lA[r * LDSTR + c] = *(const short8*)&Ab[(size_t)(m0 + r) * K + k0 + c];
                *(short8*)&lB[r * LDSTR + c] = *(const short8*)&BT[(size_t)(n0 + r) * K + k0 + c];
            }
        }
        __syncthreads();
        #pragma unroll
        for (int ks = 0; ks < 2; ++ks) {
            const int fk = ((lane >> 4) << 3) + ks * 32;  // quad*8 + kstep
            const int fr = lane & 15;
            short8 af[4], bf[4];
            #pragma unroll
            for (int i = 0; i < 4; ++i) af[i] = *(short8*)&lA[(wm + i * 16 + fr) * LDSTR + fk];
            #pragma unroll
            for (int j = 0; j < 4; ++j) bf[j] = *(short8*)&lB[(wn + j * 16 + fr) * LDSTR + fk];
            #pragma unroll
            for (int i = 0; i < 4; ++i)
                #pragma unroll
                for (int j = 0; j < 4; ++j)
                    acc[i][j] = __builtin_amdgcn_mfma_f32_16x16x32_bf16(af[i], bf[j], acc[i][j], 0, 0, 0);
        }
        __syncthreads();
    }

    const int cf = lane & 15;
    const int rb = (lane >> 4) * 4;
    #pragma unroll
    for (int j = 0; j < 4; ++j) {
        const int n = n0 + wn + j * 16 + cf;
        const float bval = bf2f(bias[n]);
        const int h = n >> 6, dh = n & 63;
        #pragma unroll
        for (int i = 0; i < 4; ++i) {
            #pragma unroll
            for (int reg = 0; reg < 4; ++reg) {
                const int m = m0 + wm + i * 16 + rb + reg;
                const float v = acc[i][j][reg] + bval;
                if (mode == 0) {
                    int b = m >> 11, s = m & (S_ - 1);
                    ((u16*)out)[((size_t)(b * H_ + h) * S_ + s) * DH_ + dh] = f2bf(v);
                } else if (mode == 1) {
                    int b = m >> 11, s = m & (S_ - 1);
                    ((u16*)out)[((size_t)(b * H_ + h) * DH_ + dh) * S_ + s] = f2bf(v);
                } else {
                    size_t off = (size_t)m * D_ + n;
                    if (ext32) ((float*)out)[off] = v;
                    else       ((u16*)out)[off] = f2bf(v);
                }
            }
        }
    }
}

// ---------------------------------------------------------------------------
// Fused flash-style attention: per (b,h, 64-row Q block):
//   pass 1: stream K tiles, online row max/sum of exp(s/8)  (no memory writes)
//   pass 2: recompute S tiles, write final normalized aws (the ONLY aws HBM
//           write in the pipeline), and (WITH_PV) accumulate P*V into ctx.
// Replaces scores_kernel + softmax_kernel (+ ctx_kernel when WITH_PV).
// Grid: 1024 blocks, 1-D, XCD-swizzled so each XCD's L2 holds 4 bh of K/V.
// ---------------------------------------------------------------------------
template<int WITH_PV>
__global__ __launch_bounds__(256, 3) void fused_attn_kernel(
    const u16* __restrict__ Qp, const u16* __restrict__ Kp,
    const u16* __restrict__ Vt, void* __restrict__ dout,
    u16* __restrict__ ctx, const unsigned int* __restrict__ flag)
{
    __shared__ u16 lQ[64 * LDSTR];
    __shared__ u16 lK[64 * LDSTR];
    __shared__ u16 lV[WITH_PV ? 64 * LDSTR : 8];
    __shared__ u16 lP[WITH_PV ? 4 * 16 * LDSTR : 8];

    const bool ext32 = flag[0] != 0;
    const int tid = threadIdx.x;
    const int wave = tid >> 6, lane = tid & 63;
    // XCD-aware swizzle: linear block id -> (bh, mblk) so that XCD g (= id%8
    // under round-robin dispatch) sees only bh in [4g, 4g+4) -> 2 MB K/V in L2.
    const int lin = blockIdx.x;
    const int g = lin & 7, ii = lin >> 3;
    const int bh = g * 4 + (ii & 3);        // 0..31
    const int mblk = ii >> 2;               // 0..31
    const int b = bh >> 4, h = bh & 15;
    const int m0 = mblk * 64;
    const int wm = wave * 16;               // wave's 16 Q rows within block
    const int fr = lane & 15;
    const int quad = lane >> 4;             // 0..3
    const int fk = quad * 8;

    const u16* Qb = Qp + (size_t)bh * S_ * DH_;
    const u16* Kb = Kp + (size_t)bh * S_ * DH_;
    const u16* Vb = Vt + (size_t)bh * DH_ * S_;

    // stage Q block (64x64) once; keep this wave's A-fragments in registers
    #pragma unroll
    for (int it = 0; it < 2; ++it) {
        int e = (it * 256 + tid) * 8;
        int r = e >> 6, c = e & 63;
        *(short8*)&lQ[r * LDSTR + c] = *(const short8*)&Qb[(size_t)(m0 + r) * DH_ + c];
    }
    __syncthreads();
    short8 aq[2];
    aq[0] = *(short8*)&lQ[(wm + fr) * LDSTR + fk];
    aq[1] = *(short8*)&lQ[(wm + fr) * LDSTR + fk + 32];

    // ---- pass 1: online max / sumexp over scaled scores s*0.125 ----
    float mrun[4], lrun[4];
    #pragma unroll
    for (int r = 0; r < 4; ++r) { mrun[r] = -1e30f; lrun[r] = 0.f; }

    for (int kt = 0; kt < S_ / 64; ++kt) {
        #pragma unroll
        for (int it = 0; it < 2; ++it) {
            int e = (it * 256 + tid) * 8;
            int r = e >> 6, c = e & 63;
            *(short8*)&lK[r * LDSTR + c] = *(const short8*)&Kb[(size_t)(kt * 64 + r) * DH_ + c];
        }
        __syncthreads();
        f32x4 sacc[4];
        #pragma unroll
        for (int j = 0; j < 4; ++j) sacc[j] = (f32x4){0.f, 0.f, 0.f, 0.f};
        #pragma unroll
        for (int ks = 0; ks < 2; ++ks)
            #pragma unroll
            for (int j = 0; j < 4; ++j) {
                short8 bk = *(short8*)&lK[(j * 16 + fr) * LDSTR + fk + ks * 32];
                sacc[j] = __builtin_amdgcn_mfma_f32_16x16x32_bf16(aq[ks], bk, sacc[j], 0, 0, 0);
            }
        __syncthreads();  // lK reads done; next iteration may restage

        #pragma unroll
        for (int r = 0; r < 4; ++r) {
            float pm = fmaxf(fmaxf(sacc[0][r], sacc[1][r]), fmaxf(sacc[2][r], sacc[3][r]));
            #pragma unroll
            for (int off = 1; off < 16; off <<= 1) pm = fmaxf(pm, __shfl_xor(pm, off, 64));
            const float mnew = fmaxf(mrun[r], pm * 0.125f);
            float t = 0.f;
            #pragma unroll
            for (int j = 0; j < 4; ++j)
                t += __expf(fmaf(sacc[j][r], 0.125f, -mnew));
            #pragma unroll
            for (int off = 1; off < 16; off <<= 1) t += __shfl_xor(t, off, 64);
            lrun[r] = lrun[r] * __expf(mrun[r] - mnew) + t;
            mrun[r] = mnew;
        }
    }

    float inv[4];
    #pragma unroll
    for (int r = 0; r < 4; ++r) inv[r] = 1.f / lrun[r];

    f32x4 pv[4];
    if (WITH_PV) {
        #pragma unroll
        for (int j = 0; j < 4; ++j) pv[j] = (f32x4){0.f, 0.f, 0.f, 0.f};
    }

    float* awF = (float*)dout + OUT_ELEMS + (size_t)(h * B_ + b) * S_ * S_;
    u16*  awH = (u16*)dout + OUT_ELEMS + (size_t)(h * B_ + b) * S_ * S_;

    // ---- pass 2: recompute S (bitwise identical), write aws, accumulate PV ----
    for (int kt = 0; kt < S_ / 64; ++kt) {
        #pragma unroll
        for (int it = 0; it < 2; ++it) {
            int e = (it * 256 + tid) * 8;
            int r = e >> 6, c = e & 63;
            *(short8*)&lK[r * LDSTR + c] = *(const short8*)&Kb[(size_t)(kt * 64 + r) * DH_ + c];
            if (WITH_PV)
                *(short8*)&lV[r * LDSTR + c] = *(const short8*)&Vb[(size_t)r * S_ + kt * 64 + c];
        }
        __syncthreads();
        f32x4 sacc[4];
        #pragma unroll
        for (int j = 0; j < 4; ++j) sacc[j] = (f32x4){0.f, 0.f, 0.f, 0.f};
        #pragma unroll
        for (int ks = 0; ks < 2; ++ks)
            #pragma unroll
            for (int j = 0; j < 4; ++j) {
                short8 bk = *(short8*)&lK[(j * 16 + fr) * LDSTR + fk + ks * 32];
                sacc[j] = __builtin_amdgcn_mfma_f32_16x16x32_bf16(aq[ks], bk, sacc[j], 0, 0, 0);
            }

        // p = exp(s/8 - m) / l  (final normalized prob, fp32): write aws + LDS P
        #pragma unroll
        for (int j = 0; j < 4; ++j) {
            const int col = kt * 64 + j * 16 + fr;
            #pragma unroll
            for (int r = 0; r < 4; ++r) {
                const float p = __expf(fmaf(sacc[j][r], 0.125f, -mrun[r])) * inv[r];
                const int row = m0 + wm + quad * 4 + r;
                if (ext32) awF[(size_t)row * S_ + col] = p;
                else       awH[(size_t)row * S_ + col] = f2bf(p);
                if (WITH_PV) lP[(wm + quad * 4 + r) * LDSTR + j * 16 + fr] = f2bf(p);
            }
        }
        if (WITH_PV) {
            // P tile is wave-private: LDS RAW needs only lgkmcnt drain, no barrier
            asm volatile("s_waitcnt lgkmcnt(0)" ::: "memory");
            __builtin_amdgcn_sched_barrier(0);
            #pragma unroll
            for (int ks = 0; ks < 2; ++ks) {
                short8 ap = *(short8*)&lP[(wm + fr) * LDSTR + fk + ks * 32];
                #pragma unroll
                for (int j = 0; j < 4; ++j) {
                    short8 bv = *(short8*)&lV[(j * 16 + fr) * LDSTR + fk + ks * 32];
                    pv[j] = __builtin_amdgcn_mfma_f32_16x16x32_bf16(ap, bv, pv[j], 0, 0, 0);
                }
            }
        }
        __syncthreads();  // lK/lV reads done; next iteration restages
    }

    if (WITH_PV) {
        #pragma unroll
        for (int j = 0; j < 4; ++j) {
            const int dh = j * 16 + fr;
            #pragma unroll
            for (int r = 0; r < 4; ++r) {
                const int mrow = m0 + wm + quad * 4 + r;
                ctx[((size_t)(b * S_ + mrow)) * D_ + h * DH_ + dh] = f2bf(pv[j][r]);
            }
        }
    }
}

// ---------------------------------------------------------------------------
// ctx = aw (2048x2048) * V with B-operand Vt[dh][s]. Fallback path only
// (used when the workspace is too small for a separate ctx buffer).
// ---------------------------------------------------------------------------
__global__ __launch_bounds__(128) void ctx_kernel(
    const void* __restrict__ dout, const u16* __restrict__ Vt, u16* __restrict__ ctx,
    const unsigned int* __restrict__ flag)
{
    __shared__ u16 lA[128 * LDSTR];
    __shared__ u16 lB[64 * LDSTR];
    const bool ext32 = flag[0] != 0;
    const int tid = threadIdx.x;
    const int wave = tid >> 6, lane = tid & 63;
    const int bh = blockIdx.z, b = bh >> 4, h = bh & 15;
    const int m0 = blockIdx.x * 128;
    const int wm = wave * 64;
    const size_t abase = (size_t)(h * B_ + b) * S_ * S_;
    const u16* Bv = Vt + (size_t)bh * DH_ * S_;

    f32x4 acc[4][4];
    #pragma unroll
    for (int i = 0; i < 4; ++i)
        #pragma unroll
        for (int j = 0; j < 4; ++j)
            acc[i][j] = (f32x4){0.f, 0.f, 0.f, 0.f};

    for (int k0 = 0; k0 < S_; k0 += 64) {
        if (ext32) {
            const float* Awf = (const float*)dout + OUT_ELEMS + abase;
            #pragma unroll
            for (int it = 0; it < 8; ++it) {
                int e = (it * 128 + tid) * 8;
                int r = e >> 6, c = e & 63;
                const float4 f0 = *(const float4*)&Awf[(size_t)(m0 + r) * S_ + k0 + c];
                const float4 f1 = *(const float4*)&Awf[(size_t)(m0 + r) * S_ + k0 + c + 4];
                short8 o;
                o[0] = (short)f2bf(f0.x); o[1] = (short)f2bf(f0.y);
                o[2] = (short)f2bf(f0.z); o[3] = (short)f2bf(f0.w);
                o[4] = (short)f2bf(f1.x); o[5] = (short)f2bf(f1.y);
                o[6] = (short)f2bf(f1.z); o[7] = (short)f2bf(f1.w);
                *(short8*)&lA[r * LDSTR + c] = o;
            }
        } else {
            const u16* Awb = (const u16*)dout + OUT_ELEMS + abase;
            #pragma unroll
            for (int it = 0; it < 8; ++it) {
                int e = (it * 128 + tid) * 8;
                int r = e >> 6, c = e & 63;
                *(short8*)&lA[r * LDSTR + c] = *(const short8*)&Awb[(size_t)(m0 + r) * S_ + k0 + c];
            }
        }
        #pragma unroll
        for (int it = 0; it < 4; ++it) {
            int e = (it * 128 + tid) * 8;
            int r = e >> 6, c = e & 63;
            *(short8*)&lB[r * LDSTR + c] = *(const short8*)&Bv[(size_t)r * S_ + k0 + c];
        }
        __syncthreads();
        #pragma unroll
        for (int ks = 0; ks < 2; ++ks) {
            const int fk = ((lane >> 4) << 3) + ks * 32;
            const int fr = lane & 15;
            short8 af[4], bf[4];
            #pragma unroll
            for (int i = 0; i < 4; ++i) af[i] = *(short8*)&lA[(wm + i * 16 + fr) * LDSTR + fk];
            #pragma unroll
            for (int j = 0; j < 4; ++j) bf[j] = *(short8*)&lB[(j * 16 + fr) * LDSTR + fk];
            #pragma unroll
            for (int i = 0; i < 4; ++i)
                #pragma unroll
                for (int j = 0; j < 4; ++j)
                    acc[i][j] = __builtin_amdgcn_mfma_f32_16x16x32_bf16(af[i], bf[j], acc[i][j], 0, 0, 0);
        }
        __syncthreads();
    }

    const int cf = lane & 15;
    const int rb = (lane >> 4) * 4;
    #pragma unroll
    for (int j = 0; j < 4; ++j) {
        const int n = j * 16 + cf;  // dh
        #pragma unroll
        for (int i = 0; i < 4; ++i) {
            #pragma unroll
            for (int reg = 0; reg < 4; ++reg) {
                const int m = m0 + wm + i * 16 + rb + reg;  // s
                ctx[((size_t)(b * S_ + m)) * D_ + h * DH_ + n] = f2bf(acc[i][j][reg]);
            }
        }
    }
}

// ---------------------------------------------------------------------------
extern "C" void kernel_launch(void* const* d_in, const int* in_sizes, int n_in,
                              void* d_out, int out_size, void* d_ws, size_t ws_size,
                              hipStream_t stream)
{
    const void* q  = d_in[0];
    const void* k  = d_in[1];
    const void* v  = d_in[2];
    const void* Wq = d_in[3];
    const void* Wk = d_in[4];
    const void* Wv = d_in[5];
    const void* bq = d_in[6];
    const void* bk = d_in[7];
    const void* bv = d_in[8];
    const void* Wo = d_in[9];
    const void* bo = d_in[10];

    u16* ws   = (u16*)d_ws;
    u16* WqT  = ws;                  // 1,048,576 elems
    u16* WkT  = ws + 1048576;
    u16* WvT  = ws + 2097152;
    u16* WoT  = ws + 3145728;
    u16* Qp   = ws + 4194304;        // [b][h][s][dh]
    u16* Kp   = ws + 8388608;        // [b][h][s][dh]
    u16* Vt   = ws + 12582912;       // [b][h][dh][s]
    u16* biasB = ws + 16777216;      // bq|bk|bv|bo bf16, 4096 elems
    unsigned int* flag = (unsigned int*)(ws + 16781312);
    u16* ctxws = ws + 16781376;      // [b*s][h*64+dh], 4,194,304 elems (8 MB)

    // full-fusion path needs ctxws to fit in the workspace
    const bool big_ws = ws_size >= (size_t)(16781376 + 4194304) * sizeof(u16);
    u16* ctxbuf = big_ws ? ctxws : Qp;  // fallback: ctx_kernel writes into dead Qp

    detect_kernel<<<1, 64, 0, stream>>>(q, flag);
    convert_bias_kernel<<<dim3(1, 4), 256, 0, stream>>>(bq, bk, bv, bo, biasB, flag);
    transpose_weights_kernel<<<dim3(256, 4), 256, 0, stream>>>(
        Wq, Wk, Wv, Wo, WqT, WkT, WvT, WoT, flag);
    gemm_bias_kernel<<<dim3(32, 8), 256, 0, stream>>>(q, WqT, biasB,        Qp, 4096, 1024, 0, 1, flag);
    gemm_bias_kernel<<<dim3(32, 8), 256, 0, stream>>>(k, WkT, biasB + 1024, Kp, 4096, 1024, 0, 1, flag);
    gemm_bias_kernel<<<dim3(32, 8), 256, 0, stream>>>(v, WvT, biasB + 2048, Vt, 4096, 1024, 1, 1, flag);

    if (big_ws) {
        fused_attn_kernel<1><<<dim3(1024), 256, 0, stream>>>(Qp, Kp, Vt, d_out, ctxws, flag);
    } else {
        fused_attn_kernel<0><<<dim3(1024), 256, 0, stream>>>(Qp, Kp, Vt, d_out, nullptr, flag);
        ctx_kernel<<<dim3(16, 1, 32), 128, 0, stream>>>(d_out, Vt, Qp, flag);
    }
    gemm_bias_kernel<<<dim3(32, 8), 256, 0, stream>>>(ctxbuf, WoT, biasB + 3072, d_out, 4096, 1024, 2, 0, flag);
}

// Round 2
// 799.189 us; speedup vs baseline: 1.4569x; 1.0755x over previous
//
#include <hip/hip_runtime.h>
#include <hip/hip_bf16.h>
#include <cstdint>
#include <cstddef>

#define B_  2
#define S_  2048
#define D_  1024
#define H_  16
#define DH_ 64
#define OUT_ELEMS ((size_t)B_ * S_ * D_)   // 4,194,304; aws follows in d_out

typedef unsigned short u16;
typedef __attribute__((ext_vector_type(8))) short short8;
typedef __attribute__((ext_vector_type(4))) float f32x4;

__device__ __forceinline__ float bf2f(u16 u) {
    union { unsigned int i; float f; } x;
    x.i = ((unsigned int)u) << 16;
    return x.f;
}
__device__ __forceinline__ u16 f2bf(float f) {
    union { float f; unsigned int i; } x; x.f = f;
    unsigned int r = x.i + 0x7fffu + ((x.i >> 16) & 1u);  // round-to-nearest-even
    return (u16)(r >> 16);
}

#define LDSTR 72   // 64 + 8 pad; 144 B row stride (16B-aligned, 2-way bank alias = free)
#define LDTR  136  // epilogue-transpose stride; 272 B row (16B-aligned)

// ---------------------------------------------------------------------------
// Dtype probe: flag=1 => external data is fp32.
// ---------------------------------------------------------------------------
__global__ __launch_bounds__(64) void detect_kernel(const void* q, unsigned int* flag)
{
    const int lane = threadIdx.x;
    const u16 e = ((const u16*)q)[lane * 2];
    const float v = bf2f(e);
    const float a = fabsf(v);
    const bool wild = !(a <= 100.f) || (a != 0.f && a < 1e-6f);  // !(a<=100) catches NaN
    unsigned long long m = __ballot(wild);
    if (lane == 0) *flag = (__popcll(m) >= 16) ? 1u : 0u;
}

// ---------------------------------------------------------------------------
// Convert the 4 bias vectors (1024 elems each) to bf16 in ws.
// ---------------------------------------------------------------------------
__global__ __launch_bounds__(256) void convert_bias_kernel(
    const void* bq, const void* bk, const void* bv, const void* bo,
    u16* __restrict__ dst, const unsigned int* __restrict__ flag)
{
    const bool ext32 = flag[0] != 0;
    const int which = blockIdx.y;
    const void* src = which == 0 ? bq : which == 1 ? bk : which == 2 ? bv : bo;
    u16* d = dst + which * 1024;
    const int tid = threadIdx.x;
    #pragma unroll
    for (int i = 0; i < 4; ++i) {
        const int idx = i * 256 + tid;
        d[idx] = ext32 ? f2bf(((const float*)src)[idx]) : ((const u16*)src)[idx];
    }
}

// ---------------------------------------------------------------------------
// Transpose weights into N x K bf16 layout via 64x64 LDS tiles.
// which<3: W (H,D,DH) -> WT[n=h*64+dh][d]   which==3: Wo (D,D) -> WoT[n][d]
// ---------------------------------------------------------------------------
__global__ __launch_bounds__(256) void transpose_weights_kernel(
    const void* Wq, const void* Wk, const void* Wv, const void* Wo,
    u16* __restrict__ WqT, u16* __restrict__ WkT,
    u16* __restrict__ WvT, u16* __restrict__ WoT,
    const unsigned int* __restrict__ flag)
{
    __shared__ u16 t[64][65];
    const bool ext32 = flag[0] != 0;
    const int which = blockIdx.y;
    const void* src = which == 0 ? Wq : which == 1 ? Wk : which == 2 ? Wv : Wo;
    u16* dst = which == 0 ? WqT : which == 1 ? WkT : which == 2 ? WvT : WoT;
    const int tile = blockIdx.x;            // 0..255
    const int tid = threadIdx.x;
    const int rr = tid >> 6;                // 0..3
    const int cc = tid & 63;                // 0..63

    if (which < 3) {
        const int h = tile >> 4, d0 = (tile & 15) * 64;
        #pragma unroll
        for (int i = 0; i < 16; ++i) {
            int r = rr + i * 4;
            size_t idx = ((size_t)(h * 1024 + d0 + r)) * 64 + cc;     // W[h][d0+r][cc]
            t[r][cc] = ext32 ? f2bf(((const float*)src)[idx]) : ((const u16*)src)[idx];
        }
        __syncthreads();
        #pragma unroll
        for (int i = 0; i < 16; ++i) {
            int c = rr + i * 4;  // dh
            dst[((size_t)(h * 64 + c)) * 1024 + d0 + cc] = t[cc][c];  // WT[h*64+c][d0+cc]
        }
    } else {
        const int d0 = (tile >> 4) * 64, n0 = (tile & 15) * 64;
        #pragma unroll
        for (int i = 0; i < 16; ++i) {
            int r = rr + i * 4;
            size_t idx = (size_t)(d0 + r) * 1024 + n0 + cc;           // Wo[d0+r][n0+cc]
            t[r][cc] = ext32 ? f2bf(((const float*)src)[idx]) : ((const u16*)src)[idx];
        }
        __syncthreads();
        #pragma unroll
        for (int i = 0; i < 16; ++i) {
            int c = rr + i * 4;
            dst[(size_t)(n0 + c) * 1024 + d0 + cc] = t[cc][c];        // WoT[n0+c][d0+cc]
        }
    }
}

// ---------------------------------------------------------------------------
// Merged Q/K/V projection GEMM: z selects input/weight/bias/output.
// 128x128 tile; epilogue round-trips through LDS for coalesced short8 stores.
// z<2: out[b][h][s][dh] bf16      z==2: Vt[b][h][dh][s] bf16 (transposed tile)
// ---------------------------------------------------------------------------
__global__ __launch_bounds__(256) void qkv_gemm_kernel(
    const void* __restrict__ qin, const void* __restrict__ kin, const void* __restrict__ vin,
    const u16* __restrict__ WqT, const u16* __restrict__ WkT, const u16* __restrict__ WvT,
    const u16* __restrict__ biasB,
    u16* __restrict__ Qp, u16* __restrict__ Kp, u16* __restrict__ Vt,
    const unsigned int* __restrict__ flag)
{
    __shared__ u16 lds[2 * 128 * LDSTR];   // lA | lB in main loop; lT (128x136) in epilogue
    u16* lA = lds;
    u16* lB = lds + 128 * LDSTR;
    const bool ext32 = flag[0] != 0;
    const int z = blockIdx.z;
    const void* A = z == 0 ? qin : z == 1 ? kin : vin;
    const u16* BT = z == 0 ? WqT : z == 1 ? WkT : WvT;
    const u16* bias = biasB + z * 1024;
    const int tid = threadIdx.x;
    const int wave = tid >> 6, lane = tid & 63;
    const int m0 = blockIdx.x * 128, n0 = blockIdx.y * 128;
    const int wm = (wave >> 1) * 64, wn = (wave & 1) * 64;
    const int K = 1024;

    f32x4 acc[4][4];
    #pragma unroll
    for (int i = 0; i < 4; ++i)
        #pragma unroll
        for (int j = 0; j < 4; ++j)
            acc[i][j] = (f32x4){0.f, 0.f, 0.f, 0.f};

    for (int k0 = 0; k0 < K; k0 += 64) {
        if (ext32) {
            const float* Af = (const float*)A;
            #pragma unroll
            for (int it = 0; it < 4; ++it) {
                int e = (it * 256 + tid) * 8;
                int r = e >> 6, c = e & 63;
                const float4 f0 = *(const float4*)&Af[(size_t)(m0 + r) * K + k0 + c];
                const float4 f1 = *(const float4*)&Af[(size_t)(m0 + r) * K + k0 + c + 4];
                short8 o;
                o[0] = (short)f2bf(f0.x); o[1] = (short)f2bf(f0.y);
                o[2] = (short)f2bf(f0.z); o[3] = (short)f2bf(f0.w);
                o[4] = (short)f2bf(f1.x); o[5] = (short)f2bf(f1.y);
                o[6] = (short)f2bf(f1.z); o[7] = (short)f2bf(f1.w);
                *(short8*)&lA[r * LDSTR + c] = o;
                *(short8*)&lB[r * LDSTR + c] = *(const short8*)&BT[(size_t)(n0 + r) * K + k0 + c];
            }
        } else {
            const u16* Ab = (const u16*)A;
            #pragma unroll
            for (int it = 0; it < 4; ++it) {
                int e = (it * 256 + tid) * 8;
                int r = e >> 6, c = e & 63;
                *(short8*)&lA[r * LDSTR + c] = *(const short8*)&Ab[(size_t)(m0 + r) * K + k0 + c];
                *(short8*)&lB[r * LDSTR + c] = *(const short8*)&BT[(size_t)(n0 + r) * K + k0 + c];
            }
        }
        __syncthreads();
        #pragma unroll
        for (int ks = 0; ks < 2; ++ks) {
            const int fk = ((lane >> 4) << 3) + ks * 32;
            const int fr = lane & 15;
            short8 af[4], bf[4];
            #pragma unroll
            for (int i = 0; i < 4; ++i) af[i] = *(short8*)&lA[(wm + i * 16 + fr) * LDSTR + fk];
            #pragma unroll
            for (int j = 0; j < 4; ++j) bf[j] = *(short8*)&lB[(wn + j * 16 + fr) * LDSTR + fk];
            #pragma unroll
            for (int i = 0; i < 4; ++i)
                #pragma unroll
                for (int j = 0; j < 4; ++j)
                    acc[i][j] = __builtin_amdgcn_mfma_f32_16x16x32_bf16(af[i], bf[j], acc[i][j], 0, 0, 0);
        }
        __syncthreads();
    }

    // ---- epilogue: LDS transpose for coalesced stores ----
    u16* lT = lds;   // 128 x LDTR (17408 u16 <= 18432 available)
    const int cf = lane & 15;
    const int rb = (lane >> 4) * 4;
    if (z < 2) {
        // lT[m_local][n_local]
        #pragma unroll
        for (int j = 0; j < 4; ++j) {
            const int nl = wn + j * 16 + cf;
            const float bval = bf2f(bias[n0 + nl]);
            #pragma unroll
            for (int i = 0; i < 4; ++i)
                #pragma unroll
                for (int reg = 0; reg < 4; ++reg) {
                    const int ml = wm + i * 16 + rb + reg;
                    lT[ml * LDTR + nl] = f2bf(acc[i][j][reg] + bval);
                }
        }
        __syncthreads();
        u16* out = z == 0 ? Qp : Kp;
        #pragma unroll
        for (int it = 0; it < 8; ++it) {
            const int idx = (it * 256 + tid) * 8;
            const int row = idx >> 7, col = idx & 127;
            const int m = m0 + row, n = n0 + col;
            const int b = m >> 11, s = m & (S_ - 1), h = n >> 6, dh = n & 63;
            *(short8*)&out[((size_t)(b * H_ + h) * S_ + s) * DH_ + dh] =
                *(const short8*)&lT[row * LDTR + col];
        }
    } else {
        // lT[n_local][m_local] (transposed): Vt rows = dh, cols = s
        #pragma unroll
        for (int j = 0; j < 4; ++j) {
            const int nl = wn + j * 16 + cf;
            const float bval = bf2f(bias[n0 + nl]);
            #pragma unroll
            for (int i = 0; i < 4; ++i)
                #pragma unroll
                for (int reg = 0; reg < 4; ++reg) {
                    const int ml = wm + i * 16 + rb + reg;
                    lT[nl * LDTR + ml] = f2bf(acc[i][j][reg] + bval);
                }
        }
        __syncthreads();
        #pragma unroll
        for (int it = 0; it < 8; ++it) {
            const int idx = (it * 256 + tid) * 8;
            const int row = idx >> 7, col = idx & 127;   // row=n_local, col=m_local
            const int n = n0 + row, m = m0 + col;
            const int b = m >> 11, s = m & (S_ - 1), h = n >> 6, dh = n & 63;
            *(short8*)&Vt[((size_t)(b * H_ + h) * DH_ + dh) * S_ + s] =
                *(const short8*)&lT[row * LDTR + col];
        }
    }
}

// ---------------------------------------------------------------------------
// 128x128-tile bf16 MFMA GEMM (final output projection only, mode 2).
// ---------------------------------------------------------------------------
__global__ __launch_bounds__(256) void gemm_bias_kernel(
    const void* __restrict__ A, const u16* __restrict__ BT,
    const u16* __restrict__ bias, void* __restrict__ out,
    int M, int K, const unsigned int* __restrict__ flag)
{
    __shared__ u16 lA[128 * LDSTR];
    __shared__ u16 lB[128 * LDSTR];
    const bool ext32 = flag[0] != 0;
    const int tid = threadIdx.x;
    const int wave = tid >> 6, lane = tid & 63;
    const int m0 = blockIdx.x * 128, n0 = blockIdx.y * 128;
    const int wm = (wave >> 1) * 64, wn = (wave & 1) * 64;

    f32x4 acc[4][4];
    #pragma unroll
    for (int i = 0; i < 4; ++i)
        #pragma unroll
        for (int j = 0; j < 4; ++j)
            acc[i][j] = (f32x4){0.f, 0.f, 0.f, 0.f};

    for (int k0 = 0; k0 < K; k0 += 64) {
        const u16* Ab = (const u16*)A;
        #pragma unroll
        for (int it = 0; it < 4; ++it) {
            int e = (it * 256 + tid) * 8;
            int r = e >> 6, c = e & 63;
            *(short8*)&lA[r * LDSTR + c] = *(const short8*)&Ab[(size_t)(m0 + r) * K + k0 + c];
            *(short8*)&lB[r * LDSTR + c] = *(const short8*)&BT[(size_t)(n0 + r) * K + k0 + c];
        }
        __syncthreads();
        #pragma unroll
        for (int ks = 0; ks < 2; ++ks) {
            const int fk = ((lane >> 4) << 3) + ks * 32;
            const int fr = lane & 15;
            short8 af[4], bf[4];
            #pragma unroll
            for (int i = 0; i < 4; ++i) af[i] = *(short8*)&lA[(wm + i * 16 + fr) * LDSTR + fk];
            #pragma unroll
            for (int j = 0; j < 4; ++j) bf[j] = *(short8*)&lB[(wn + j * 16 + fr) * LDSTR + fk];
            #pragma unroll
            for (int i = 0; i < 4; ++i)
                #pragma unroll
                for (int j = 0; j < 4; ++j)
                    acc[i][j] = __builtin_amdgcn_mfma_f32_16x16x32_bf16(af[i], bf[j], acc[i][j], 0, 0, 0);
        }
        __syncthreads();
    }

    const int cf = lane & 15;
    const int rb = (lane >> 4) * 4;
    #pragma unroll
    for (int j = 0; j < 4; ++j) {
        const int n = n0 + wn + j * 16 + cf;
        const float bval = bf2f(bias[n]);
        #pragma unroll
        for (int i = 0; i < 4; ++i) {
            #pragma unroll
            for (int reg = 0; reg < 4; ++reg) {
                const int m = m0 + wm + i * 16 + rb + reg;
                const float v = acc[i][j][reg] + bval;
                size_t off = (size_t)m * D_ + n;
                if (ext32) ((float*)out)[off] = v;
                else       ((u16*)out)[off] = f2bf(v);
            }
        }
    }
}

// ---------------------------------------------------------------------------
// Fused flash-style attention (scores + softmax + aws write + PV).
// pass 1: per-lane online (m,l) over the lane's own 4 cols/tile — zero
//         cross-lane ops in the loop; single 16-lane (m,l)-combine at end.
// pass 2: recompute S (deterministic, identical), write final normalized aws
//         once, accumulate P*V. lQ and lP overlay (wave-private row ranges).
// ---------------------------------------------------------------------------
template<int WITH_PV>
__global__ __launch_bounds__(256, 3) void fused_attn_kernel(
    const u16* __restrict__ Qp, const u16* __restrict__ Kp,
    const u16* __restrict__ Vt, void* __restrict__ dout,
    u16* __restrict__ ctx, const unsigned int* __restrict__ flag)
{
    __shared__ u16 sh[(WITH_PV ? 3 : 2) * 64 * LDSTR];
    u16* lK  = sh;
    u16* lQP = sh + 64 * LDSTR;                    // lQ at start; lP in pass 2 (wave-private rows)
    u16* lV  = WITH_PV ? sh + 2 * 64 * LDSTR : sh; // unused when !WITH_PV

    const bool ext32 = flag[0] != 0;
    const int tid = threadIdx.x;
    const int wave = tid >> 6, lane = tid & 63;
    // XCD-aware swizzle: round-robin dispatch -> XCD g sees bh in [4g,4g+4).
    const int lin = blockIdx.x;
    const int g = lin & 7, ii = lin >> 3;
    const int bh = g * 4 + (ii & 3);        // 0..31
    const int mblk = ii >> 2;               // 0..31
    const int b = bh >> 4, h = bh & 15;
    const int m0 = mblk * 64;
    const int wm = wave * 16;               // wave's 16 Q rows within block
    const int fr = lane & 15;
    const int quad = lane >> 4;             // 0..3
    const int fk = quad * 8;

    const u16* Qb = Qp + (size_t)bh * S_ * DH_;
    const u16* Kb = Kp + (size_t)bh * S_ * DH_;
    const u16* Vb = Vt + (size_t)bh * DH_ * S_;

    // stage Q block (64x64) once; keep this wave's A-fragments in registers
    #pragma unroll
    for (int it = 0; it < 2; ++it) {
        int e = (it * 256 + tid) * 8;
        int r = e >> 6, c = e & 63;
        *(short8*)&lQP[r * LDSTR + c] = *(const short8*)&Qb[(size_t)(m0 + r) * DH_ + c];
    }
    __syncthreads();
    short8 aq[2];
    aq[0] = *(short8*)&lQP[(wm + fr) * LDSTR + fk];
    aq[1] = *(short8*)&lQP[(wm + fr) * LDSTR + fk + 32];

    // ---- pass 1: per-lane online max / sumexp (scores scaled by 0.125) ----
    float mrun[4], lrun[4];
    #pragma unroll
    for (int r = 0; r < 4; ++r) { mrun[r] = -1e30f; lrun[r] = 0.f; }

    for (int kt = 0; kt < S_ / 64; ++kt) {
        #pragma unroll
        for (int it = 0; it < 2; ++it) {
            int e = (it * 256 + tid) * 8;
            int r = e >> 6, c = e & 63;
            *(short8*)&lK[r * LDSTR + c] = *(const short8*)&Kb[(size_t)(kt * 64 + r) * DH_ + c];
        }
        __syncthreads();
        f32x4 sacc[4];
        #pragma unroll
        for (int j = 0; j < 4; ++j) sacc[j] = (f32x4){0.f, 0.f, 0.f, 0.f};
        #pragma unroll
        for (int ks = 0; ks < 2; ++ks)
            #pragma unroll
            for (int j = 0; j < 4; ++j) {
                short8 bk = *(short8*)&lK[(j * 16 + fr) * LDSTR + fk + ks * 32];
                sacc[j] = __builtin_amdgcn_mfma_f32_16x16x32_bf16(aq[ks], bk, sacc[j], 0, 0, 0);
            }
        __syncthreads();  // lK reads done; next iteration restages

        #pragma unroll
        for (int r = 0; r < 4; ++r) {
            const float pm = fmaxf(fmaxf(sacc[0][r], sacc[1][r]),
                                   fmaxf(sacc[2][r], sacc[3][r])) * 0.125f;
            const float mnew = fmaxf(mrun[r], pm);
            float t = __expf(fmaf(sacc[0][r], 0.125f, -mnew))
                    + __expf(fmaf(sacc[1][r], 0.125f, -mnew))
                    + __expf(fmaf(sacc[2][r], 0.125f, -mnew))
                    + __expf(fmaf(sacc[3][r], 0.125f, -mnew));
            lrun[r] = lrun[r] * __expf(mrun[r] - mnew) + t;
            mrun[r] = mnew;
        }
    }

    // single cross-lane (m,l) combine: 16 lanes sharing each row (same quad)
    float inv[4];
    #pragma unroll
    for (int r = 0; r < 4; ++r) {
        #pragma unroll
        for (int off = 1; off < 16; off <<= 1) {
            const float mo = __shfl_xor(mrun[r], off, 64);
            const float lo = __shfl_xor(lrun[r], off, 64);
            const float mn = fmaxf(mrun[r], mo);
            lrun[r] = lrun[r] * __expf(mrun[r] - mn) + lo * __expf(mo - mn);
            mrun[r] = mn;
        }
        inv[r] = 1.f / lrun[r];
    }

    f32x4 pv[4];
    if (WITH_PV) {
        #pragma unroll
        for (int j = 0; j < 4; ++j) pv[j] = (f32x4){0.f, 0.f, 0.f, 0.f};
    }

    float* awF = (float*)dout + OUT_ELEMS + (size_t)(h * B_ + b) * S_ * S_;
    u16*  awH = (u16*)dout + OUT_ELEMS + (size_t)(h * B_ + b) * S_ * S_;

    // ---- pass 2: recompute S, write aws, accumulate PV ----
    for (int kt = 0; kt < S_ / 64; ++kt) {
        #pragma unroll
        for (int it = 0; it < 2; ++it) {
            int e = (it * 256 + tid) * 8;
            int r = e >> 6, c = e & 63;
            *(short8*)&lK[r * LDSTR + c] = *(const short8*)&Kb[(size_t)(kt * 64 + r) * DH_ + c];
            if (WITH_PV)
                *(short8*)&lV[r * LDSTR + c] = *(const short8*)&Vb[(size_t)r * S_ + kt * 64 + c];
        }
        __syncthreads();
        f32x4 sacc[4];
        #pragma unroll
        for (int j = 0; j < 4; ++j) sacc[j] = (f32x4){0.f, 0.f, 0.f, 0.f};
        #pragma unroll
        for (int ks = 0; ks < 2; ++ks)
            #pragma unroll
            for (int j = 0; j < 4; ++j) {
                short8 bk = *(short8*)&lK[(j * 16 + fr) * LDSTR + fk + ks * 32];
                sacc[j] = __builtin_amdgcn_mfma_f32_16x16x32_bf16(aq[ks], bk, sacc[j], 0, 0, 0);
            }

        // p = exp(s/8 - m) / l : write aws + (WITH_PV) wave-private LDS P tile
        #pragma unroll
        for (int j = 0; j < 4; ++j) {
            const int col = kt * 64 + j * 16 + fr;
            #pragma unroll
            for (int r = 0; r < 4; ++r) {
                const float p = __expf(fmaf(sacc[j][r], 0.125f, -mrun[r])) * inv[r];
                const int row = m0 + wm + quad * 4 + r;
                if (ext32) awF[(size_t)row * S_ + col] = p;
                else       awH[(size_t)row * S_ + col] = f2bf(p);
                if (WITH_PV) lQP[(wm + quad * 4 + r) * LDSTR + j * 16 + fr] = f2bf(p);
            }
        }
        if (WITH_PV) {
            // P tile is wave-private: LDS RAW needs only lgkmcnt drain, no barrier
            asm volatile("s_waitcnt lgkmcnt(0)" ::: "memory");
            __builtin_amdgcn_sched_barrier(0);
            #pragma unroll
            for (int ks = 0; ks < 2; ++ks) {
                short8 ap = *(short8*)&lQP[(wm + fr) * LDSTR + fk + ks * 32];
                #pragma unroll
                for (int j = 0; j < 4; ++j) {
                    short8 bv = *(short8*)&lV[(j * 16 + fr) * LDSTR + fk + ks * 32];
                    pv[j] = __builtin_amdgcn_mfma_f32_16x16x32_bf16(ap, bv, pv[j], 0, 0, 0);
                }
            }
        }
        __syncthreads();  // lK/lV reads done; next iteration restages
    }

    if (WITH_PV) {
        #pragma unroll
        for (int j = 0; j < 4; ++j) {
            const int dh = j * 16 + fr;
            #pragma unroll
            for (int r = 0; r < 4; ++r) {
                const int mrow = m0 + wm + quad * 4 + r;
                ctx[((size_t)(b * S_ + mrow)) * D_ + h * DH_ + dh] = f2bf(pv[j][r]);
            }
        }
    }
}

// ---------------------------------------------------------------------------
// ctx = aw (2048x2048) * V with B-operand Vt[dh][s]. Fallback path only.
// ---------------------------------------------------------------------------
__global__ __launch_bounds__(128) void ctx_kernel(
    const void* __restrict__ dout, const u16* __restrict__ Vt, u16* __restrict__ ctx,
    const unsigned int* __restrict__ flag)
{
    __shared__ u16 lA[128 * LDSTR];
    __shared__ u16 lB[64 * LDSTR];
    const bool ext32 = flag[0] != 0;
    const int tid = threadIdx.x;
    const int wave = tid >> 6, lane = tid & 63;
    const int bh = blockIdx.z, b = bh >> 4, h = bh & 15;
    const int m0 = blockIdx.x * 128;
    const int wm = wave * 64;
    const size_t abase = (size_t)(h * B_ + b) * S_ * S_;
    const u16* Bv = Vt + (size_t)bh * DH_ * S_;

    f32x4 acc[4][4];
    #pragma unroll
    for (int i = 0; i < 4; ++i)
        #pragma unroll
        for (int j = 0; j < 4; ++j)
            acc[i][j] = (f32x4){0.f, 0.f, 0.f, 0.f};

    for (int k0 = 0; k0 < S_; k0 += 64) {
        if (ext32) {
            const float* Awf = (const float*)dout + OUT_ELEMS + abase;
            #pragma unroll
            for (int it = 0; it < 8; ++it) {
                int e = (it * 128 + tid) * 8;
                int r = e >> 6, c = e & 63;
                const float4 f0 = *(const float4*)&Awf[(size_t)(m0 + r) * S_ + k0 + c];
                const float4 f1 = *(const float4*)&Awf[(size_t)(m0 + r) * S_ + k0 + c + 4];
                short8 o;
                o[0] = (short)f2bf(f0.x); o[1] = (short)f2bf(f0.y);
                o[2] = (short)f2bf(f0.z); o[3] = (short)f2bf(f0.w);
                o[4] = (short)f2bf(f1.x); o[5] = (short)f2bf(f1.y);
                o[6] = (short)f2bf(f1.z); o[7] = (short)f2bf(f1.w);
                *(short8*)&lA[r * LDSTR + c] = o;
            }
        } else {
            const u16* Awb = (const u16*)dout + OUT_ELEMS + abase;
            #pragma unroll
            for (int it = 0; it < 8; ++it) {
                int e = (it * 128 + tid) * 8;
                int r = e >> 6, c = e & 63;
                *(short8*)&lA[r * LDSTR + c] = *(const short8*)&Awb[(size_t)(m0 + r) * S_ + k0 + c];
            }
        }
        #pragma unroll
        for (int it = 0; it < 4; ++it) {
            int e = (it * 128 + tid) * 8;
            int r = e >> 6, c = e & 63;
            *(short8*)&lB[r * LDSTR + c] = *(const short8*)&Bv[(size_t)r * S_ + k0 + c];
        }
        __syncthreads();
        #pragma unroll
        for (int ks = 0; ks < 2; ++ks) {
            const int fk = ((lane >> 4) << 3) + ks * 32;
            const int fr = lane & 15;
            short8 af[4], bf[4];
            #pragma unroll
            for (int i = 0; i < 4; ++i) af[i] = *(short8*)&lA[(wm + i * 16 + fr) * LDSTR + fk];
            #pragma unroll
            for (int j = 0; j < 4; ++j) bf[j] = *(short8*)&lB[(j * 16 + fr) * LDSTR + fk];
            #pragma unroll
            for (int i = 0; i < 4; ++i)
                #pragma unroll
                for (int j = 0; j < 4; ++j)
                    acc[i][j] = __builtin_amdgcn_mfma_f32_16x16x32_bf16(af[i], bf[j], acc[i][j], 0, 0, 0);
        }
        __syncthreads();
    }

    const int cf = lane & 15;
    const int rb = (lane >> 4) * 4;
    #pragma unroll
    for (int j = 0; j < 4; ++j) {
        const int n = j * 16 + cf;  // dh
        #pragma unroll
        for (int i = 0; i < 4; ++i) {
            #pragma unroll
            for (int reg = 0; reg < 4; ++reg) {
                const int m = m0 + wm + i * 16 + rb + reg;  // s
                ctx[((size_t)(b * S_ + m)) * D_ + h * DH_ + n] = f2bf(acc[i][j][reg]);
            }
        }
    }
}

// ---------------------------------------------------------------------------
extern "C" void kernel_launch(void* const* d_in, const int* in_sizes, int n_in,
                              void* d_out, int out_size, void* d_ws, size_t ws_size,
                              hipStream_t stream)
{
    const void* q  = d_in[0];
    const void* k  = d_in[1];
    const void* v  = d_in[2];
    const void* Wq = d_in[3];
    const void* Wk = d_in[4];
    const void* Wv = d_in[5];
    const void* bq = d_in[6];
    const void* bk = d_in[7];
    const void* bv = d_in[8];
    const void* Wo = d_in[9];
    const void* bo = d_in[10];

    u16* ws   = (u16*)d_ws;
    u16* WqT  = ws;                  // 1,048,576 elems
    u16* WkT  = ws + 1048576;
    u16* WvT  = ws + 2097152;
    u16* WoT  = ws + 3145728;
    u16* Qp   = ws + 4194304;        // [b][h][s][dh]
    u16* Kp   = ws + 8388608;        // [b][h][s][dh]
    u16* Vt   = ws + 12582912;       // [b][h][dh][s]
    u16* biasB = ws + 16777216;      // bq|bk|bv|bo bf16, 4096 elems
    unsigned int* flag = (unsigned int*)(ws + 16781312);
    u16* ctxws = ws + 16781376;      // [b*s][h*64+dh], 4,194,304 elems (8 MB)

    // full-fusion path needs ctxws to fit in the workspace
    const bool big_ws = ws_size >= (size_t)(16781376 + 4194304) * sizeof(u16);
    u16* ctxbuf = big_ws ? ctxws : Qp;  // fallback: ctx_kernel writes into dead Qp

    detect_kernel<<<1, 64, 0, stream>>>(q, flag);
    convert_bias_kernel<<<dim3(1, 4), 256, 0, stream>>>(bq, bk, bv, bo, biasB, flag);
    transpose_weights_kernel<<<dim3(256, 4), 256, 0, stream>>>(
        Wq, Wk, Wv, Wo, WqT, WkT, WvT, WoT, flag);
    qkv_gemm_kernel<<<dim3(32, 8, 3), 256, 0, stream>>>(
        q, k, v, WqT, WkT, WvT, biasB, Qp, Kp, Vt, flag);

    if (big_ws) {
        fused_attn_kernel<1><<<dim3(1024), 256, 0, stream>>>(Qp, Kp, Vt, d_out, ctxws, flag);
    } else {
        fused_attn_kernel<0><<<dim3(1024), 256, 0, stream>>>(Qp, Kp, Vt, d_out, nullptr, flag);
        ctx_kernel<<<dim3(16, 1, 32), 128, 0, stream>>>(d_out, Vt, Qp, flag);
    }
    gemm_bias_kernel<<<dim3(32, 8), 256, 0, stream>>>(ctxbuf, WoT, biasB + 3072, d_out, 4096, 1024, flag);
}